// Round 4
// baseline (47.711 us; speedup 1.0000x reference)
//
#include <hip/hip_runtime.h>
#include <hip/hip_bf16.h>
#include <stdint.h>

// pooled[b,i,:] = bias + sum_{j!=i} W_cell(b,i,j) . hid[b,j,:]
// Per (batch, chunk-of-8-cells) block:
//   stage1: Zt[j][ho] = hid[b,j] . W_c[ho]  (MFMA, A=W from L2, B=H hoisted regs)
//   stage2: gather    acc[i][ho] += Zt[j][ho] for j in list[i][c]  (bucketed lists)
// Zt is XOR-swizzled ((j&7)<<4 on byte offset) for conflict-free writes+reads.
// W-fragment loads are pipelined one cell ahead (issue after MFMA, consume after
// pack+barrier+gather). Deterministic list build (count/prefix/place by ascending j).

typedef __attribute__((ext_vector_type(8))) short bf16x8;
typedef __attribute__((ext_vector_type(4))) float f32x4;

#define NCHUNK 8   // cell chunks -> 64*NCHUNK blocks
#define CPB 8      // cells per block

__device__ inline unsigned short bf16bits(float x) {
    __hip_bfloat16 h = __float2bfloat16(x);
    return *reinterpret_cast<unsigned short*>(&h);
}
__device__ inline float bf2f(short u) {
    union { unsigned int i; float f; } v;
    v.i = ((unsigned int)(unsigned short)u) << 16;
    return v.f;
}

// ---- P1: W f32 [128][8192] -> Wb bf16 [c=64][hg=16][ho=128][e=8] ----
__global__ __launch_bounds__(512)
void gp_wconv(const float* __restrict__ W, __hip_bfloat16* __restrict__ Wb)
{
    __shared__ __attribute__((aligned(16))) __hip_bfloat16 Wl[128][136];
    const int c = blockIdx.x, t = threadIdx.x;
    #pragma unroll
    for (int q = 0; q < 8; ++q) {
        int flat = q * 512 + t;
        int ho = flat >> 5, k4 = flat & 31;
        float4 v = *(const float4*)(W + (size_t)ho * 8192 + c * 128 + k4 * 4);
        __hip_bfloat16* d = &Wl[ho][k4 * 4];
        d[0] = __float2bfloat16(v.x); d[1] = __float2bfloat16(v.y);
        d[2] = __float2bfloat16(v.z); d[3] = __float2bfloat16(v.w);
    }
    __syncthreads();
    #pragma unroll
    for (int q = 0; q < 4; ++q) {
        int flat = q * 512 + t;            // flat = hg*128 + ho
        int hg = flat >> 7, ho = flat & 127;
        bf16x8 v = *(const bf16x8*)&Wl[ho][hg * 8];
        *(bf16x8*)(Wb + (size_t)c * 16384 + (size_t)flat * 8) = v;
    }
}

// ---- main fused kernel: grid = NCHUNK*64, block = 512 (8 waves) ----
__global__ __launch_bounds__(512, 4)
void gp_main(const float* __restrict__ hid, const float* __restrict__ pos,
             const __hip_bfloat16* __restrict__ Wb, float* __restrict__ partial)
{
    __shared__ __attribute__((aligned(16))) __hip_bfloat16 Hs[16 * 64 * 8]; // [hg][j][e] 16KB
    __shared__ __attribute__((aligned(16))) __hip_bfloat16 Zt[2][64 * 128]; // [j][ho^swz] 2x16KB
    __shared__ unsigned char cellt[64 * 64];   // [i][j]
    __shared__ unsigned char listj[64 * 64];   // [i][n] bucketed by c
    __shared__ unsigned char cnt8[64][8];
    __shared__ unsigned char offs[64][9];
    __shared__ float ps[128];

    const int t = threadIdx.x;
    const int b = blockIdx.x & 63, chunk = blockIdx.x >> 6;
    const int w = t >> 6, lane = t & 63;
    const int l15 = lane & 15, kg = lane >> 4;
    const int wm = w & 3, wn = w >> 2;     // wm: ho-group of 32; wn: j-group of 32

    if (t < 128) ps[t] = pos[(size_t)b * 128 + t];
    __syncthreads();

    // cell table (trunc-toward-zero, clip, gx-major; self = 255)
    #pragma unroll
    for (int q = 0; q < 8; ++q) {
        int idx = q * 512 + t;
        int i = idx >> 6, j = idx & 63;
        float rx = ps[j * 2 + 0] - ps[i * 2 + 0];
        float ry = ps[j * 2 + 1] - ps[i * 2 + 1];
        int gx = (int)((rx + 2.0f) * 2.0f);
        int gy = (int)((ry + 2.0f) * 2.0f);
        gx = gx < 0 ? 0 : (gx > 7 ? 7 : gx);
        gy = gy < 0 ? 0 : (gy > 7 ? 7 : gy);
        cellt[idx] = (i == j) ? 255 : (unsigned char)(gx * 8 + gy);
    }
    // stage hid[b] -> Hs [hg][j][e]
    #pragma unroll
    for (int q = 0; q < 2; ++q) {
        int idx = q * 512 + t;
        int hg = idx >> 6, j = idx & 63;
        const float* src = hid + ((size_t)b * 64 + j) * 128 + hg * 8;
        float4 v0 = *(const float4*)src;
        float4 v1 = *(const float4*)(src + 4);
        __hip_bfloat16* d = &Hs[(hg * 64 + j) * 8];
        d[0] = __float2bfloat16(v0.x); d[1] = __float2bfloat16(v0.y);
        d[2] = __float2bfloat16(v0.z); d[3] = __float2bfloat16(v0.w);
        d[4] = __float2bfloat16(v1.x); d[5] = __float2bfloat16(v1.y);
        d[6] = __float2bfloat16(v1.z); d[7] = __float2bfloat16(v1.w);
    }
    __syncthreads();

    // hoist H B-fragments (col=j=l15, k=hg*8+e): 8 frags = 32 VGPR
    bf16x8 hf[2][4];
    #pragma unroll
    for (int ks = 0; ks < 4; ++ks) {
        int hg = ks * 4 + kg;
        hf[0][ks] = *(const bf16x8*)&Hs[(hg * 64 + wn * 32 + l15) * 8];
        hf[1][ks] = *(const bf16x8*)&Hs[(hg * 64 + wn * 32 + 16 + l15) * 8];
    }

    // ---- deterministic bucketed list build ----
    {   // count: thread (i = t>>3, c = t&7)
        int i = t >> 3, c = t & 7;
        int target = chunk * 8 + c;
        int n = 0;
        for (int j = 0; j < 64; ++j) n += (cellt[i * 64 + j] == target);
        cnt8[i][c] = (unsigned char)n;
    }
    __syncthreads();
    if (t < 64) {   // prefix over c
        int s = 0;
        offs[t][0] = 0;
        #pragma unroll
        for (int c = 0; c < 8; ++c) { s += cnt8[t][c]; offs[t][c + 1] = (unsigned char)s; }
    }
    __syncthreads();
    {   // place (ascending j per (i,c) -> deterministic sum order)
        int i = t >> 3, c = t & 7;
        int target = chunk * 8 + c;
        int n = offs[i][c];
        for (int j = 0; j < 64; ++j)
            if (cellt[i * 64 + j] == target) listj[i * 64 + (n++)] = (unsigned char)j;
    }

    // preload W A-fragments for first cell (row=ho=l15-based, k=hg*8+e)
    bf16x8 wf[2][4];
    {
        const __hip_bfloat16* wc = Wb + (size_t)(chunk * 8) * 16384;
        #pragma unroll
        for (int ks = 0; ks < 4; ++ks) {
            int hg = ks * 4 + kg;
            wf[0][ks] = *(const bf16x8*)(wc + ((size_t)hg * 128 + wm * 32 + l15) * 8);
            wf[1][ks] = *(const bf16x8*)(wc + ((size_t)hg * 128 + wm * 32 + 16 + l15) * 8);
        }
    }

    float acc[2][8];
    #pragma unroll
    for (int p4 = 0; p4 < 2; ++p4)
        #pragma unroll
        for (int e = 0; e < 8; ++e) acc[p4][e] = 0.f;

    const int hog = lane & 15, ig = lane >> 4;   // gather role: 4 i's x 16 ho-groups
    __syncthreads();   // lists ready

    for (int cc = 0; cc < CPB; ++cc) {
        const int p = cc & 1;

        // gather previous cell from Zt[p^1] (covers in-flight wf loads)
        if (cc > 0) {
            const int cl = cc - 1;
            #pragma unroll
            for (int p4 = 0; p4 < 2; ++p4) {
                int i = w * 8 + p4 * 4 + ig;
                int n1 = offs[i][cl + 1];
                for (int n = offs[i][cl]; n < n1; ++n) {
                    int j = listj[i * 64 + n];
                    int boff = (hog * 16) ^ ((j & 7) << 4);
                    bf16x8 v = *(const bf16x8*)((const char*)&Zt[p ^ 1][0] + j * 256 + boff);
                    #pragma unroll
                    for (int e = 0; e < 8; ++e) acc[p4][e] += bf2f(v[e]);
                }
            }
        }

        // stage1 MFMA: z[fm][fn], M=ho, N=j
        f32x4 z[2][2];
        #pragma unroll
        for (int fm = 0; fm < 2; ++fm)
            #pragma unroll
            for (int fn = 0; fn < 2; ++fn) z[fm][fn] = (f32x4){0.f, 0.f, 0.f, 0.f};
        #pragma unroll
        for (int ks = 0; ks < 4; ++ks) {
            z[0][0] = __builtin_amdgcn_mfma_f32_16x16x32_bf16(wf[0][ks], hf[0][ks], z[0][0], 0, 0, 0);
            z[0][1] = __builtin_amdgcn_mfma_f32_16x16x32_bf16(wf[0][ks], hf[1][ks], z[0][1], 0, 0, 0);
            z[1][0] = __builtin_amdgcn_mfma_f32_16x16x32_bf16(wf[1][ks], hf[0][ks], z[1][0], 0, 0, 0);
            z[1][1] = __builtin_amdgcn_mfma_f32_16x16x32_bf16(wf[1][ks], hf[1][ks], z[1][1], 0, 0, 0);
        }

        // pack z -> Zt[p]: D col=l15=j, rows=ho0+kg*4+r (4 consecutive ho per lane)
        #pragma unroll
        for (int fm = 0; fm < 2; ++fm) {
            #pragma unroll
            for (int fn = 0; fn < 2; ++fn) {
                int j   = wn * 32 + fn * 16 + l15;
                int ho0 = wm * 32 + fm * 16 + kg * 4;
                int boff = (ho0 * 2) ^ ((j & 7) << 4);
                union { unsigned short us[4]; uint2 v; } pk;
                pk.us[0] = bf16bits(z[fm][fn][0]);
                pk.us[1] = bf16bits(z[fm][fn][1]);
                pk.us[2] = bf16bits(z[fm][fn][2]);
                pk.us[3] = bf16bits(z[fm][fn][3]);
                *(uint2*)((char*)&Zt[p][0] + j * 256 + boff) = pk.v;
            }
        }

        // issue next cell's W loads (consumed after pack+barrier+gather)
        if (cc < CPB - 1) {
            const __hip_bfloat16* wc = Wb + (size_t)(chunk * 8 + cc + 1) * 16384;
            #pragma unroll
            for (int ks = 0; ks < 4; ++ks) {
                int hg = ks * 4 + kg;
                wf[0][ks] = *(const bf16x8*)(wc + ((size_t)hg * 128 + wm * 32 + l15) * 8);
                wf[1][ks] = *(const bf16x8*)(wc + ((size_t)hg * 128 + wm * 32 + 16 + l15) * 8);
            }
        }
        __syncthreads();
    }

    // final gather (cell CPB-1 in Zt[(CPB-1)&1])
    {
        const int cl = CPB - 1;
        #pragma unroll
        for (int p4 = 0; p4 < 2; ++p4) {
            int i = w * 8 + p4 * 4 + ig;
            int n1 = offs[i][cl + 1];
            for (int n = offs[i][cl]; n < n1; ++n) {
                int j = listj[i * 64 + n];
                int boff = (hog * 16) ^ ((j & 7) << 4);
                bf16x8 v = *(const bf16x8*)((const char*)&Zt[(CPB - 1) & 1][0] + j * 256 + boff);
                #pragma unroll
                for (int e = 0; e < 8; ++e) acc[p4][e] += bf2f(v[e]);
            }
        }
    }

    // epilogue: partial[chunk][b][i][ho]
    float* pb = partial + (((size_t)chunk * 64 + b) * 64) * 128;
    #pragma unroll
    for (int p4 = 0; p4 < 2; ++p4) {
        int i = w * 8 + p4 * 4 + ig;
        float4 v0 = make_float4(acc[p4][0], acc[p4][1], acc[p4][2], acc[p4][3]);
        float4 v1 = make_float4(acc[p4][4], acc[p4][5], acc[p4][6], acc[p4][7]);
        *(float4*)(pb + (size_t)i * 128 + hog * 8) = v0;
        *(float4*)(pb + (size_t)i * 128 + hog * 8 + 4) = v1;
    }
}

// ---- reduce: out = bias + sum_chunk partial ----
__global__ __launch_bounds__(512)
void gp_reduce(const float* __restrict__ partial, const float* __restrict__ bias,
               float* __restrict__ out)
{
    int gid = blockIdx.x * 512 + threadIdx.x;  // 131072 float4s
    int ho4 = gid & 31;
    float4 a = *(const float4*)(bias + ho4 * 4);
    #pragma unroll
    for (int ch = 0; ch < NCHUNK; ++ch) {
        float4 v = *(const float4*)(partial + (size_t)ch * 524288 + (size_t)gid * 4);
        a.x += v.x; a.y += v.y; a.z += v.z; a.w += v.w;
    }
    *(float4*)(out + (size_t)gid * 4) = a;
}

extern "C" void kernel_launch(void* const* d_in, const int* in_sizes, int n_in,
                              void* d_out, int out_size, void* d_ws, size_t ws_size,
                              hipStream_t stream)
{
    const float* hid  = (const float*)d_in[0];  // [64,64,128]
    const float* pos  = (const float*)d_in[1];  // [64,64,2]
    const float* W    = (const float*)d_in[2];  // [128,8192]
    const float* bias = (const float*)d_in[3];  // [128]
    float* out = (float*)d_out;

    __hip_bfloat16* Wb = (__hip_bfloat16*)d_ws;                 // 2 MB
    float* partial = (float*)((char*)d_ws + (size_t)2097152);   // 16 MB

    hipLaunchKernelGGL(gp_wconv,  dim3(64),          dim3(512), 0, stream, W, Wb);
    hipLaunchKernelGGL(gp_main,   dim3(NCHUNK * 64), dim3(512), 0, stream, hid, pos, Wb, partial);
    hipLaunchKernelGGL(gp_reduce, dim3(256),         dim3(512), 0, stream, partial, bias, out);
}

// Round 5
// 37.927 us; speedup vs baseline: 1.2580x; 1.2580x over previous
//
#include <hip/hip_runtime.h>
#include <hip/hip_bf16.h>
#include <stdint.h>

// pooled[b,i,:] = bias + sum_{j!=i} W_cell(b,i,j) . hid[b,j,:]
// Per (batch, chunk-of-8-cells) block, per cell cc:
//   stage Ws[cc+1] (global_load_lds, double-buffered, issued BEFORE compute so
//     the vmcnt(0) drain at the barrier lands after ~800cy of compute)
//   z    = H(regs) @ Ws[cc] (LDS)   16 MFMA/wave
//   pack z -> Zt[p], build mask Ms[p], barrier
//   acc += Ms[p] @ Zt[p]            8 MFMA/wave
// One barrier per cell. LDS 135KB -> 1 block/CU (8 waves), latency hidden by
// the software pipeline rather than TLP.

typedef __attribute__((ext_vector_type(8))) short bf16x8;
typedef __attribute__((ext_vector_type(4))) float f32x4;

#define NCHUNK 8   // cell chunks -> 64*NCHUNK = 512 blocks
#define CPB 8      // cells per block

__device__ inline void load_lds16(const void* g, void* l) {
    __builtin_amdgcn_global_load_lds(
        (const __attribute__((address_space(1))) unsigned int*)g,
        (__attribute__((address_space(3))) unsigned int*)l, 16, 0, 0);
}

__device__ inline unsigned short bf16bits(float x) {
    __hip_bfloat16 h = __float2bfloat16(x);
    return *reinterpret_cast<unsigned short*>(&h);
}

// ---- P1: W f32 [128][8192] -> Wb bf16 [c=64][hg=16][ho=128][e=8] ----
__global__ __launch_bounds__(512)
void gp_wconv(const float* __restrict__ W, __hip_bfloat16* __restrict__ Wb)
{
    __shared__ __attribute__((aligned(16))) __hip_bfloat16 Wl[128][136];
    const int c = blockIdx.x, t = threadIdx.x;
    #pragma unroll
    for (int q = 0; q < 8; ++q) {
        int flat = q * 512 + t;
        int ho = flat >> 5, k4 = flat & 31;
        float4 v = *(const float4*)(W + (size_t)ho * 8192 + c * 128 + k4 * 4);
        __hip_bfloat16* d = &Wl[ho][k4 * 4];
        d[0] = __float2bfloat16(v.x); d[1] = __float2bfloat16(v.y);
        d[2] = __float2bfloat16(v.z); d[3] = __float2bfloat16(v.w);
    }
    __syncthreads();
    #pragma unroll
    for (int q = 0; q < 4; ++q) {
        int flat = q * 512 + t;            // flat = hg*128 + ho
        int hg = flat >> 7, ho = flat & 127;
        bf16x8 v = *(const bf16x8*)&Wl[ho][hg * 8];
        *(bf16x8*)(Wb + (size_t)c * 16384 + (size_t)flat * 8) = v;
    }
}

// ---- main fused kernel: grid = NCHUNK*64, block = 512 (8 waves) ----
__global__ __launch_bounds__(512, 2)
void gp_main(const float* __restrict__ hid, const float* __restrict__ pos,
             const __hip_bfloat16* __restrict__ Wb, float* __restrict__ partial)
{
    __shared__ __attribute__((aligned(16))) __hip_bfloat16 Ws[2][16 * 128 * 8]; // [hg][ho][e] 2x32KB
    __shared__ __attribute__((aligned(16))) __hip_bfloat16 Hs[16 * 64 * 8];     // [hg][j][e]  16KB
    __shared__ __attribute__((aligned(16))) __hip_bfloat16 Zt[2][8 * 128 * 8];  // [jg][ho][e] 2x16KB
    __shared__ __attribute__((aligned(16))) __hip_bfloat16 Ms[2][8 * 64 * 8];   // [jg][i][e]  2x8KB
    __shared__ unsigned char cellt[64 * 64];                                    // [i][j] 4KB
    __shared__ float ps[128];

    const int t = threadIdx.x;
    const int b = blockIdx.x & 63, chunk = blockIdx.x >> 6;
    const int w = t >> 6, lane = t & 63;
    const int l15 = lane & 15, kg = lane >> 4;   // 16x16x32 frag: row/col=l15, k-group=kg
    const int mw = w & 1, nw = w >> 1;           // wave tile: j rows mw*32.., ho cols nw*32..

    if (t < 128) ps[t] = pos[(size_t)b * 128 + t];
    __syncthreads();

    // cell table (trunc-toward-zero, clip, gx-major; self = 255)
    #pragma unroll
    for (int q = 0; q < 8; ++q) {
        int idx = q * 512 + t;
        int i = idx >> 6, j = idx & 63;
        float rx = ps[j * 2 + 0] - ps[i * 2 + 0];
        float ry = ps[j * 2 + 1] - ps[i * 2 + 1];
        int gx = (int)((rx + 2.0f) * 2.0f);
        int gy = (int)((ry + 2.0f) * 2.0f);
        gx = gx < 0 ? 0 : (gx > 7 ? 7 : gx);
        gy = gy < 0 ? 0 : (gy > 7 ? 7 : gy);
        cellt[idx] = (i == j) ? 255 : (unsigned char)(gx * 8 + gy);
    }
    // stage hid[b] -> Hs [hg][j][e]
    #pragma unroll
    for (int q = 0; q < 2; ++q) {
        int idx = q * 512 + t;
        int hg = idx >> 6, j = idx & 63;
        const float* src = hid + ((size_t)b * 64 + j) * 128 + hg * 8;
        float4 v0 = *(const float4*)src;
        float4 v1 = *(const float4*)(src + 4);
        __hip_bfloat16* d = &Hs[(hg * 64 + j) * 8];
        d[0] = __float2bfloat16(v0.x); d[1] = __float2bfloat16(v0.y);
        d[2] = __float2bfloat16(v0.z); d[3] = __float2bfloat16(v0.w);
        d[4] = __float2bfloat16(v1.x); d[5] = __float2bfloat16(v1.y);
        d[6] = __float2bfloat16(v1.z); d[7] = __float2bfloat16(v1.w);
    }

    // prologue stage: Ws[0] <- cell chunk*8+0 (async, drained at next barrier)
    {
        const char* gsrc = (const char*)(Wb + (size_t)(chunk * 8) * 16384);
        #pragma unroll
        for (int q = 0; q < 4; ++q) {
            int off = q * 8192 + t * 16;
            load_lds16(gsrc + off, (char*)&Ws[0][0] + off);
        }
    }
    __syncthreads();   // cellt/Hs visible; Ws[0] drained (compiler vmcnt(0))

    // hoist H A-fragments (M=j): 8 frags = 32 VGPR
    bf16x8 afr[2][4];
    #pragma unroll
    for (int ks = 0; ks < 4; ++ks) {
        int hg = ks * 4 + kg;
        afr[0][ks] = *(const bf16x8*)&Hs[(hg * 64 + mw * 32 + l15) * 8];
        afr[1][ks] = *(const bf16x8*)&Hs[(hg * 64 + mw * 32 + 16 + l15) * 8];
    }

    f32x4 acc[2][2];
    #pragma unroll
    for (int fm = 0; fm < 2; ++fm)
        #pragma unroll
        for (int fn = 0; fn < 2; ++fn)
            acc[fm][fn] = (f32x4){0.f, 0.f, 0.f, 0.f};

    #pragma unroll 2
    for (int cc = 0; cc < CPB; ++cc) {
        const int p = cc & 1;
        const int c = chunk * CPB + cc;

        // issue next cell's staging FIRST (consumed after z+pack+Ms+barrier)
        if (cc < CPB - 1) {
            const char* gsrc = (const char*)(Wb + (size_t)(c + 1) * 16384);
            #pragma unroll
            for (int q = 0; q < 4; ++q) {
                int off = q * 8192 + t * 16;
                load_lds16(gsrc + off, (char*)&Ws[p ^ 1][0] + off);
            }
        }

        // build M_c [jg][i][e] into ping-pong buffer
        {
            int i = t & 63, jg = t >> 6;
            const unsigned char* cr = &cellt[i * 64 + jg * 8];
            __hip_bfloat16* d = &Ms[p][(jg * 64 + i) * 8];
            #pragma unroll
            for (int e = 0; e < 8; ++e)
                d[e] = __float2bfloat16(cr[e] == c ? 1.0f : 0.0f);
        }

        // z-phase: z = Hs(A: row=j) @ Ws[p](B: col=ho), 16 MFMA/wave
        f32x4 z[2][2];
        #pragma unroll
        for (int fm = 0; fm < 2; ++fm)
            #pragma unroll
            for (int fn = 0; fn < 2; ++fn) z[fm][fn] = (f32x4){0.f, 0.f, 0.f, 0.f};
        #pragma unroll
        for (int ks = 0; ks < 4; ++ks) {
            int hg = ks * 4 + kg;
            bf16x8 b0 = *(const bf16x8*)&Ws[p][(hg * 128 + nw * 32 + l15) * 8];
            bf16x8 b1 = *(const bf16x8*)&Ws[p][(hg * 128 + nw * 32 + 16 + l15) * 8];
            z[0][0] = __builtin_amdgcn_mfma_f32_16x16x32_bf16(afr[0][ks], b0, z[0][0], 0, 0, 0);
            z[0][1] = __builtin_amdgcn_mfma_f32_16x16x32_bf16(afr[0][ks], b1, z[0][1], 0, 0, 0);
            z[1][0] = __builtin_amdgcn_mfma_f32_16x16x32_bf16(afr[1][ks], b0, z[1][0], 0, 0, 0);
            z[1][1] = __builtin_amdgcn_mfma_f32_16x16x32_bf16(afr[1][ks], b1, z[1][1], 0, 0, 0);
        }

        // pack z -> Zt[p] [jg][ho][e] (D: col=l15=ho, rows j=base+kg*4+r)
        #pragma unroll
        for (int fm = 0; fm < 2; ++fm) {
            #pragma unroll
            for (int fn = 0; fn < 2; ++fn) {
                int j0 = mw * 32 + fm * 16 + kg * 4;
                int jg = j0 >> 3, e0 = j0 & 7;
                int ho = nw * 32 + fn * 16 + l15;
                union { unsigned short us[4]; uint2 v; } pk;
                pk.us[0] = bf16bits(z[fm][fn][0]);
                pk.us[1] = bf16bits(z[fm][fn][1]);
                pk.us[2] = bf16bits(z[fm][fn][2]);
                pk.us[3] = bf16bits(z[fm][fn][3]);
                *(uint2*)((char*)&Zt[p][0] + ((size_t)(jg * 128 + ho) * 8 + e0) * 2) = pk.v;
            }
        }
        __syncthreads();   // Zt[p]+Ms[p] visible; vmcnt drain -> Ws[p^1] ready

        // acc-phase: acc += Ms[p](A: row=i,k=j) @ Zt[p](B: col=ho,k=j)
        #pragma unroll
        for (int ks = 0; ks < 2; ++ks) {
            int jg = ks * 4 + kg;
            bf16x8 a0 = *(const bf16x8*)&Ms[p][(jg * 64 + mw * 32 + l15) * 8];
            bf16x8 a1 = *(const bf16x8*)&Ms[p][(jg * 64 + mw * 32 + 16 + l15) * 8];
            bf16x8 b0 = *(const bf16x8*)&Zt[p][(jg * 128 + nw * 32 + l15) * 8];
            bf16x8 b1 = *(const bf16x8*)&Zt[p][(jg * 128 + nw * 32 + 16 + l15) * 8];
            acc[0][0] = __builtin_amdgcn_mfma_f32_16x16x32_bf16(a0, b0, acc[0][0], 0, 0, 0);
            acc[0][1] = __builtin_amdgcn_mfma_f32_16x16x32_bf16(a0, b1, acc[0][1], 0, 0, 0);
            acc[1][0] = __builtin_amdgcn_mfma_f32_16x16x32_bf16(a1, b0, acc[1][0], 0, 0, 0);
            acc[1][1] = __builtin_amdgcn_mfma_f32_16x16x32_bf16(a1, b1, acc[1][1], 0, 0, 0);
        }
    }

    // epilogue: partial[chunk][b][i][ho]
    float* pb = partial + (((size_t)chunk * 64 + b) * 64) * 128;
    #pragma unroll
    for (int fm = 0; fm < 2; ++fm)
        #pragma unroll
        for (int fn = 0; fn < 2; ++fn)
            #pragma unroll
            for (int r = 0; r < 4; ++r) {
                int i = mw * 32 + fm * 16 + kg * 4 + r;
                int ho = nw * 32 + fn * 16 + l15;
                pb[(size_t)i * 128 + ho] = acc[fm][fn][r];
            }
}

// ---- reduce: out = bias + sum_chunk partial ----
__global__ __launch_bounds__(512)
void gp_reduce(const float* __restrict__ partial, const float* __restrict__ bias,
               float* __restrict__ out)
{
    int gid = blockIdx.x * 512 + threadIdx.x;  // 131072 float4s
    int ho4 = gid & 31;
    float4 a = *(const float4*)(bias + ho4 * 4);
    #pragma unroll
    for (int ch = 0; ch < NCHUNK; ++ch) {
        float4 v = *(const float4*)(partial + (size_t)ch * 524288 + (size_t)gid * 4);
        a.x += v.x; a.y += v.y; a.z += v.z; a.w += v.w;
    }
    *(float4*)(out + (size_t)gid * 4) = a;
}

extern "C" void kernel_launch(void* const* d_in, const int* in_sizes, int n_in,
                              void* d_out, int out_size, void* d_ws, size_t ws_size,
                              hipStream_t stream)
{
    const float* hid  = (const float*)d_in[0];  // [64,64,128]
    const float* pos  = (const float*)d_in[1];  // [64,64,2]
    const float* W    = (const float*)d_in[2];  // [128,8192]
    const float* bias = (const float*)d_in[3];  // [128]
    float* out = (float*)d_out;

    __hip_bfloat16* Wb = (__hip_bfloat16*)d_ws;                 // 2 MB
    float* partial = (float*)((char*)d_ws + (size_t)2097152);   // 16 MB

    hipLaunchKernelGGL(gp_wconv,  dim3(64),          dim3(512), 0, stream, W, Wb);
    hipLaunchKernelGGL(gp_main,   dim3(NCHUNK * 64), dim3(512), 0, stream, hid, pos, Wb, partial);
    hipLaunchKernelGGL(gp_reduce, dim3(256),         dim3(512), 0, stream, partial, bias, out);
}